// Round 3
// baseline (125.747 us; speedup 1.0000x reference)
//
#include <hip/hip_runtime.h>
#include <hip/hip_bf16.h>

// Problem: B=4, C=256, N=4096 (16^3).
// out[b,c,n] = sum_m relu(cos(x_n,x_m))^2 * (W x + b)[c,m]
// Decomposition: xn = x/||x|| (bf16) -> S = xn^T xn, P = relu(S)^2,
//                T[c,m] = nrm[m]*(W xn)[c,m] + b[c],   out = T * P^T.

typedef unsigned short u16;
typedef __attribute__((ext_vector_type(8))) short short8;   // 8 bf16 = 4 VGPRs
typedef __attribute__((ext_vector_type(4))) float f32x4;

#define MFMA16(a, b, c) __builtin_amdgcn_mfma_f32_16x16x32_bf16((a), (b), (c), 0, 0, 0)

__device__ __forceinline__ u16 f2bf(float f) {
    union { float f; unsigned u; } v; v.f = f;
    unsigned u = v.u;
    u += 0x7fffu + ((u >> 16) & 1u);   // RNE
    return (u16)(u >> 16);
}

// ---------------- K0: W (fp32 256x256) -> bf16 ----------------
__global__ void k_wconv(const float* __restrict__ W, u16* __restrict__ Wbf) {
    int i = blockIdx.x * 256 + threadIdx.x;
    Wbf[i] = f2bf(W[i]);
}

// ------- K1: fused norm + transpose: one read of x ---------------------------
// 256 blocks: b = bid>>6, 64-wide n-chunk. Stage x[b][:, n0:n0+64] in LDS fp32,
// column-reduce for norms, write xfn[b][n][c] = bf16(x*1/||x||) transposed.
__global__ __launch_bounds__(256) void k_prep(const float* __restrict__ x,
                                              u16* __restrict__ xfn,
                                              float* __restrict__ nrm) {
    __shared__ float xs[256][65];     // 65 pad: conflict-free col reads
    __shared__ float part[4][64];
    __shared__ float rs_s[64];
    int bid = blockIdx.x;
    int b = bid >> 6, n0 = (bid & 63) << 6;
    int tid = threadIdx.x;
    int rowg = tid >> 4, l16 = tid & 15;
    const float* xb = x + ((size_t)b << 20) + n0;
#pragma unroll
    for (int s = 0; s < 16; ++s) {
        int row = (s << 4) + rowg;    // c index
        float4 v = *(const float4*)(xb + (size_t)row * 4096 + (l16 << 2));
        xs[row][(l16 << 2) + 0] = v.x;
        xs[row][(l16 << 2) + 1] = v.y;
        xs[row][(l16 << 2) + 2] = v.z;
        xs[row][(l16 << 2) + 3] = v.w;
    }
    __syncthreads();
    int q = tid >> 6, nl = tid & 63;
    float ss = 0.f;
#pragma unroll 16
    for (int c = 0; c < 64; ++c) {
        float v = xs[(q << 6) + c][nl];
        ss += v * v;
    }
    part[q][nl] = ss;
    __syncthreads();
    if (tid < 64) {
        float t = part[0][tid] + part[1][tid] + part[2][tid] + part[3][tid];
        float nr = sqrtf(t);
        nrm[(b << 12) + n0 + tid] = nr;
        rs_s[tid] = 1.0f / fmaxf(nr, 1e-8f);
    }
    __syncthreads();
    u16* op = xfn + ((size_t)b << 20) + (size_t)n0 * 256;
#pragma unroll
    for (int s2 = 0; s2 < 4; ++s2) {
        int n = (s2 << 4) + rowg;
        float rsv = rs_s[n];
        u16 tmp[16];
#pragma unroll
        for (int j = 0; j < 16; ++j)
            tmp[j] = f2bf(xs[(l16 << 4) + j][n] * rsv);
        *(short8*)(op + (size_t)n * 256 + (l16 << 4)) = *(const short8*)(&tmp[0]);
        *(short8*)(op + (size_t)n * 256 + (l16 << 4) + 8) = *(const short8*)(&tmp[8]);
    }
}

// ---------------- K2: tb[b][c][n] = nrm[n]*(W xn)[c,n] + bias[c] ------------
__global__ __launch_bounds__(256) void k_tgemm(const u16* __restrict__ Wbf,
                                               const u16* __restrict__ xfn,
                                               const float* __restrict__ bias,
                                               const float* __restrict__ nrm,
                                               u16* __restrict__ tb) {
    int bid = blockIdx.x;
    int batch = bid >> 7, nt = bid & 127;
    int n0 = nt << 5;
    const u16* xf_b = xfn + ((size_t)batch << 20);
    u16* tb_b = tb + ((size_t)batch << 20);
    int tid = threadIdx.x, wid = tid >> 6, lane = tid & 63, lg = lane >> 4, lr = lane & 15;

    f32x4 zero = {0.f, 0.f, 0.f, 0.f};
    f32x4 acc[4][2];
#pragma unroll
    for (int ci = 0; ci < 4; ++ci)
#pragma unroll
        for (int nj = 0; nj < 2; ++nj) acc[ci][nj] = zero;

#pragma unroll
    for (int kc = 0; kc < 8; ++kc) {
        short8 bfr[2], afr[4];
#pragma unroll
        for (int nj = 0; nj < 2; ++nj)
            bfr[nj] = *(const short8*)(xf_b + (size_t)(n0 + (nj << 4) + lr) * 256 + (kc << 5) + (lg << 3));
#pragma unroll
        for (int ci = 0; ci < 4; ++ci)
            afr[ci] = *(const short8*)(Wbf + (size_t)((wid << 6) + (ci << 4) + lr) * 256 + (kc << 5) + (lg << 3));
#pragma unroll
        for (int ci = 0; ci < 4; ++ci) {
            acc[ci][0] = MFMA16(afr[ci], bfr[0], acc[ci][0]);
            acc[ci][1] = MFMA16(afr[ci], bfr[1], acc[ci][1]);
        }
    }
    float nrmv[2];
#pragma unroll
    for (int nj = 0; nj < 2; ++nj)
        nrmv[nj] = nrm[(batch << 12) + n0 + (nj << 4) + lr];
#pragma unroll
    for (int ci = 0; ci < 4; ++ci) {
        int cb = (wid << 6) + (ci << 4) + (lg << 2);
#pragma unroll
        for (int r = 0; r < 4; ++r) {
            float bv = bias[cb + r];
#pragma unroll
            for (int nj = 0; nj < 2; ++nj)
                tb_b[(size_t)(cb + r) * 4096 + n0 + (nj << 4) + lr] = f2bf(acc[ci][nj][r] * nrmv[nj] + bv);
        }
    }
}

// ---------------- K3: fused  O[:,ntile] = T * P^T  --------------------------
// 256 blocks (1/CU), 512 threads (8 waves). BN=BM=64.
// P-pipelined: iter t computes S[t+1] (-> lds_p[nxt]) AND consumes P[t]
// (lds_p[cur] + tb[t] regs) in one phase; ONE lgkm-only barrier per iter.
// Both dbufs' RAW/WAR hazards are ordered by that barrier. Global prefetches
// (xf[t+2], tb[t+1]) get a full body of cover and never meet a vmcnt drain.
__global__ __launch_bounds__(512, 2) void k_fused(const u16* __restrict__ xfn,
                                                  const u16* __restrict__ tb,
                                                  float* __restrict__ out) {
    __shared__ __align__(16) u16 lds_x[2][64][264];   // xf m-tile dbuf, +8 pad
    __shared__ __align__(16) u16 lds_p[2][64][72];    // P dbuf, +8 pad

    int bid = blockIdx.x;
    // XCD swizzle: batch b's 64 blocks -> XCDs {2b, 2b+1} (L2-resident panels)
    int xcd = bid & 7, grp = bid >> 3;
    int batch = xcd >> 1;
    int nt = grp + 32 * (xcd & 1);
    int n0 = nt << 6;

    const u16* xf_b = xfn + ((size_t)batch << 20);
    const u16* tb_b = tb + ((size_t)batch << 20);
    float* out_b = out + ((size_t)batch << 20);

    int tid = threadIdx.x;
    int wid = tid >> 6, lane = tid & 63, lg = lane >> 4, lr = lane & 15;
    int rt2 = wid >> 2, tc = wid & 3;   // stage A roles: row-half, col-tile
    // stage B role: wave wid owns c rows [32*wid, 32*wid+32)

    // persistent A fragments: block's 64 n-rows, full K=256 (64 VGPRs)
    short8 afrag[2][8];
#pragma unroll
    for (int ri = 0; ri < 2; ++ri) {
        const u16* p = xf_b + (size_t)(n0 + (rt2 << 5) + (ri << 4) + lr) * 256 + (lg << 3);
#pragma unroll
        for (int kc = 0; kc < 8; ++kc) afrag[ri][kc] = *(const short8*)(p + (kc << 5));
    }
    // prologue: xf[0] -> lds_x[1] (scratch), xf[1] -> lds_x[0]; tbA = tb[0]
#pragma unroll
    for (int s = 0; s < 4; ++s) {
        int idx = (s << 9) + tid, row = idx >> 5, colg = idx & 31;
        *(short8*)(&lds_x[1][row][colg << 3]) =
            *(const short8*)(xf_b + (size_t)row * 256 + (colg << 3));
        *(short8*)(&lds_x[0][row][colg << 3]) =
            *(const short8*)(xf_b + (size_t)(64 + row) * 256 + (colg << 3));
    }
    short8 tbA[2][2], tbB[2][2];
#pragma unroll
    for (int ci = 0; ci < 2; ++ci)
#pragma unroll
        for (int k2 = 0; k2 < 2; ++k2)
            tbA[ci][k2] = *(const short8*)(tb_b + (size_t)((wid << 5) + (ci << 4) + lr) * 4096
                                           + (k2 << 5) + (lg << 3));
    f32x4 zero = {0.f, 0.f, 0.f, 0.f};
    f32x4 oacc[2][4];
#pragma unroll
    for (int ci = 0; ci < 2; ++ci)
#pragma unroll
        for (int nj = 0; nj < 4; ++nj) oacc[ci][nj] = zero;
    __syncthreads();

    // prologue: S[0] from lds_x[1] -> P[0] -> lds_p[0]
    {
        f32x4 sacc0 = zero, sacc1 = zero;
#pragma unroll
        for (int kc = 0; kc < 8; ++kc) {
            short8 bfr = *(const short8*)(&lds_x[1][(tc << 4) + lr][(kc << 5) + (lg << 3)]);
            sacc0 = MFMA16(afrag[0][kc], bfr, sacc0);
            sacc1 = MFMA16(afrag[1][kc], bfr, sacc1);
        }
#pragma unroll
        for (int r = 0; r < 4; ++r) {
            float s0 = fmaxf(sacc0[r], 0.f);
            lds_p[0][(rt2 << 5) + (lg << 2) + r][(tc << 4) + lr] = f2bf(s0 * s0);
            float s1 = fmaxf(sacc1[r], 0.f);
            lds_p[0][(rt2 << 5) + 16 + (lg << 2) + r][(tc << 4) + lr] = f2bf(s1 * s1);
        }
    }
    asm volatile("s_waitcnt lgkmcnt(0)" ::: "memory");
    __builtin_amdgcn_sched_barrier(0);
    __builtin_amdgcn_s_barrier();
    __builtin_amdgcn_sched_barrier(0);

// BODY(MT): consumes P[MT] (lds_p[CUR], TBC) into oacc; computes S[MT+1] from
// lds_x[CUR] -> lds_p[CUR^1]; stages xf[MT+2] -> lds_x[CUR^1]; tbN = tb[MT+1].
#define FBODY(MT, CUR, TBC, TBN)                                                           \
    {                                                                                      \
        short8 stg[4];                                                                     \
        bool has2 = (MT) <= 61;                                                            \
        if (has2) {                                                                        \
            _Pragma("unroll")                                                              \
            for (int s = 0; s < 4; ++s) {                                                  \
                int idx = (s << 9) + tid, row = idx >> 5, colg = idx & 31;                 \
                stg[s] = *(const short8*)(xf_b + (size_t)((((MT) + 2) << 6) + row) * 256   \
                                          + (colg << 3));                                  \
            }                                                                              \
        }                                                                                  \
        _Pragma("unroll")                                                                  \
        for (int ci = 0; ci < 2; ++ci) {                                                   \
            _Pragma("unroll")                                                              \
            for (int k2 = 0; k2 < 2; ++k2)                                                 \
                TBN[ci][k2] = *(const short8*)(tb_b                                        \
                    + (size_t)((wid << 5) + (ci << 4) + lr) * 4096                         \
                    + (((MT) + 1) << 6) + (k2 << 5) + (lg << 3));                          \
        }                                                                                  \
        short8 pfr[4][2];                                                                  \
        _Pragma("unroll")                                                                  \
        for (int nj = 0; nj < 4; ++nj) {                                                   \
            pfr[nj][0] = *(const short8*)(&lds_p[CUR][(nj << 4) + lr][(lg << 3)]);         \
            pfr[nj][1] = *(const short8*)(&lds_p[CUR][(nj << 4) + lr][32 + (lg << 3)]);    \
        }                                                                                  \
        f32x4 sacc0 = zero, sacc1 = zero;                                                  \
        _Pragma("unroll")                                                                  \
        for (int kc = 0; kc < 8; ++kc) {                                                   \
            short8 bfr = *(const short8*)(&lds_x[CUR][(tc << 4) + lr][(kc << 5) + (lg << 3)]); \
            sacc0 = MFMA16(afrag[0][kc], bfr, sacc0);                                      \
            sacc1 = MFMA16(afrag[1][kc], bfr, sacc1);                                      \
        }                                                                                  \
        _Pragma("unroll")                                                                  \
        for (int ci = 0; ci < 2; ++ci) {                                                   \
            _Pragma("unroll")                                                              \
            for (int nj = 0; nj < 4; ++nj) {                                               \
                oacc[ci][nj] = MFMA16(TBC[ci][0], pfr[nj][0], oacc[ci][nj]);               \
                oacc[ci][nj] = MFMA16(TBC[ci][1], pfr[nj][1], oacc[ci][nj]);               \
            }                                                                              \
        }                                                                                  \
        _Pragma("unroll")                                                                  \
        for (int r = 0; r < 4; ++r) {                                                      \
            float s0 = fmaxf(sacc0[r], 0.f);                                               \
            lds_p[(CUR) ^ 1][(rt2 << 5) + (lg << 2) + r][(tc << 4) + lr] = f2bf(s0 * s0);  \
            float s1 = fmaxf(sacc1[r], 0.f);                                               \
            lds_p[(CUR) ^ 1][(rt2 << 5) + 16 + (lg << 2) + r][(tc << 4) + lr] = f2bf(s1 * s1); \
        }                                                                                  \
        if (has2) {                                                                        \
            _Pragma("unroll")                                                              \
            for (int s = 0; s < 4; ++s) {                                                  \
                int idx = (s << 9) + tid, row = idx >> 5, colg = idx & 31;                 \
                *(short8*)(&lds_x[(CUR) ^ 1][row][colg << 3]) = stg[s];                    \
            }                                                                              \
        }                                                                                  \
        asm volatile("s_waitcnt lgkmcnt(0)" ::: "memory");                                 \
        __builtin_amdgcn_sched_barrier(0);                                                 \
        __builtin_amdgcn_s_barrier();                                                      \
        __builtin_amdgcn_sched_barrier(0);                                                 \
    }

    for (int t = 0; t < 62; t += 2) {
        FBODY(t, 0, tbA, tbB);
        FBODY(t + 1, 1, tbB, tbA);
    }
    FBODY(62, 0, tbA, tbB);
#undef FBODY

    // epilogue iter: O[63] from lds_p[1] + tbB (no staging, no S)
    {
        short8 pfr[4][2];
#pragma unroll
        for (int nj = 0; nj < 4; ++nj) {
            pfr[nj][0] = *(const short8*)(&lds_p[1][(nj << 4) + lr][(lg << 3)]);
            pfr[nj][1] = *(const short8*)(&lds_p[1][(nj << 4) + lr][32 + (lg << 3)]);
        }
#pragma unroll
        for (int ci = 0; ci < 2; ++ci) {
#pragma unroll
            for (int nj = 0; nj < 4; ++nj) {
                oacc[ci][nj] = MFMA16(tbB[ci][0], pfr[nj][0], oacc[ci][nj]);
                oacc[ci][nj] = MFMA16(tbB[ci][1], pfr[nj][1], oacc[ci][nj]);
            }
        }
    }

    // ---- epilogue: write O fp32 ----
#pragma unroll
    for (int ci = 0; ci < 2; ++ci) {
        int c = (wid << 5) + (ci << 4) + (lg << 2);
#pragma unroll
        for (int nj = 0; nj < 4; ++nj) {
            int n = n0 + (nj << 4) + lr;
            float* op = out_b + (size_t)c * 4096 + n;
#pragma unroll
            for (int r = 0; r < 4; ++r) op[(size_t)r * 4096] = oacc[ci][nj][r];
        }
    }
}

extern "C" void kernel_launch(void* const* d_in, const int* in_sizes, int n_in,
                              void* d_out, int out_size, void* d_ws, size_t ws_size,
                              hipStream_t stream) {
    const float* x = (const float*)d_in[0];     // (4,256,16,16,16) fp32
    const float* W = (const float*)d_in[1];     // (256,256) fp32
    const float* bias = (const float*)d_in[2];  // (256,) fp32
    float* out = (float*)d_out;

    char* ws = (char*)d_ws;
    u16* xfn = (u16*)ws;                                   // 8 MiB: [B][N][C] bf16, normalized
    u16* tb = (u16*)(ws + ((size_t)8 << 20));              // 8 MiB: [B][C][N] bf16
    u16* Wbf = (u16*)(ws + ((size_t)16 << 20));            // 128 KiB
    float* nrm = (float*)(ws + ((size_t)16 << 20) + (192u << 10));  // 64 KiB

    hipLaunchKernelGGL(k_wconv, dim3(256), dim3(256), 0, stream, W, Wbf);
    hipLaunchKernelGGL(k_prep, dim3(256), dim3(256), 0, stream, x, xfn, nrm);
    hipLaunchKernelGGL(k_tgemm, dim3(512), dim3(256), 0, stream, Wbf, xfn, bias, nrm, tb);
    hipLaunchKernelGGL(k_fused, dim3(256), dim3(512), 0, stream, xfn, tb, out);
}